// Round 2
// baseline (1575.245 us; speedup 1.0000x reference)
//
#include <hip/hip_runtime.h>

// LSTMAutoRegressive: B=1024, T=1024, H1=64, H2=32, n_in=n_out=1.
// v2: 64 wgs x 512 threads (8 waves). Balanced waves: each wave owns
// 2 layer-1 tiles + 1 layer-2 tile (MFMA 16x16x32 bf16, swapped operands,
// gate-permuted A-rows, bf16 hi/lo split). Layer pipelining: step t computes
// h1[t] and h2[t-1] concurrently, sharing one set of h1[t-1] fragment reads.
// x/d prefetched in 16-step chunks (reg-staged -> LDS ping-pong). Raw
// s_barrier without vmcnt drain keeps global loads/stores off the step path.

using short8 = __attribute__((ext_vector_type(8))) short;   // 8 bf16
using f32x4  = __attribute__((ext_vector_type(4))) float;   // C/D frag
typedef unsigned short us;

#define MFMA16(A,B,C) __builtin_amdgcn_mfma_f32_16x16x32_bf16((A),(B),(C),0,0,0)
// LDS-publish barrier: wait local ops only; global loads/stores stay in flight.
#define BARRIER() asm volatile("s_waitcnt lgkmcnt(0)\n\ts_barrier" ::: "memory")

__device__ __forceinline__ us bf_hi_bits(float f){
    union { float f; unsigned u; } v; v.f = f;
    return (us)(v.u >> 16);                      // truncate to bf16
}
__device__ __forceinline__ float hi_masked(float f){
    union { float f; unsigned u; } v; v.f = f;
    v.u &= 0xFFFF0000u; return v.f;
}
__device__ __forceinline__ float sigf(float x){
    float e = __expf(-x);
    return __fdividef(1.0f, 1.0f + e);
}
__device__ __forceinline__ float tanhf_fast(float x){
    float e = __expf(-2.0f * x);
    return __fdividef(1.0f - e, 1.0f + e);
}
__device__ __forceinline__ float lstm_unit(float gi, float gf, float gg, float go, float& c){
    float ig = sigf(gi), fg = sigf(gf), gt = tanhf_fast(gg), og = sigf(go);
    c = fg * c + ig * gt;
    return og * tanhf_fast(c);
}
__device__ __forceinline__ void split_store(us* hp, us* lp, float v){
    unsigned u = __float_as_uint(v);
    *hp = (us)(u >> 16);
    float hf = __uint_as_float(u & 0xFFFF0000u);
    *lp = bf_hi_bits(v - hf);
}

__global__ __launch_bounds__(512, 2)
void lstm_ar_kernel(const float* __restrict__ x_in,
                    const float* __restrict__ dly_in,
                    const float* __restrict__ W_ih1, const float* __restrict__ W_hh1,
                    const float* __restrict__ b_ih1, const float* __restrict__ b_hh1,
                    const float* __restrict__ W_ih2, const float* __restrict__ W_hh2,
                    const float* __restrict__ b_ih2, const float* __restrict__ b_hh2,
                    const float* __restrict__ W_out, const float* __restrict__ b_out,
                    float* __restrict__ out)
{
    // h1 rows: [hi 0..63][lo 64..127], stride 136 (272B, 16B-aligned, 68w%32=4)
    // h2 rows: [hi 0..31][lo 32..63],  stride 72  (144B, 16B-aligned, 36w%32=4)
    __shared__ __align__(16) us H1[2][16][136];
    __shared__ __align__(16) us H2[2][16][72];
    // x/d chunk buffers: [buf][ts>>2][batch][ts&3]
    __shared__ __align__(16) float XB[2][4][16][4];
    __shared__ __align__(16) float DB[2][4][16][4];

    const int tid = threadIdx.x;
    const int w   = tid >> 6;          // wave 0..7
    const int l   = tid & 63;
    const int lb  = l & 15;            // A-row / batch column
    const int lq  = l >> 4;            // quarter-wave (k-window / C-row block)
    const int T   = 1024;
    const int bglob = blockIdx.x * 16 + lb;

    for (int i = tid; i < 2*16*136; i += 512) ((us*)H1)[i] = 0;
    for (int i = tid; i < 2*16*72;  i += 512) ((us*)H2)[i] = 0;

    const int ty = lb & 3, du = lb >> 2;   // gate type / unit-within-tile of A-row lb

    // ---- Layer-1 A-frags: tiles m = 2w+j, gate-row g1 = ty*64 + 4m + du ----
    short8 w1hi[2][2], w1lo[2][2];
    #pragma unroll
    for (int j = 0; j < 2; ++j)
      #pragma unroll
      for (int s = 0; s < 2; ++s)
        #pragma unroll
        for (int i = 0; i < 8; ++i) {
            int g1 = ty * 64 + 4 * (2*w + j) + du;
            float wv = W_hh1[g1 * 64 + 32*s + 8*lq + i];
            float wh = hi_masked(wv);
            w1hi[j][s][i] = (short)bf_hi_bits(wv);
            w1lo[j][s][i] = (short)bf_hi_bits(wv - wh);
        }
    // ACT-1 params: lane (lb,lq) handles unit u = 8w+4j+lq, batch lb
    float bias1[2][4], wxx[2][4], wxd[2][4];
    #pragma unroll
    for (int j = 0; j < 2; ++j)
      #pragma unroll
      for (int r = 0; r < 4; ++r) {
          int g = r * 64 + 4 * (2*w + j) + lq;
          bias1[j][r] = b_ih1[g] + b_hh1[g];
          wxx[j][r]   = W_ih1[g*2 + 0];
          wxd[j][r]   = W_ih1[g*2 + 1];
      }

    // ---- Layer-2 A-frags: tile m2 = w, gate-row g2 = ty*32 + 4w + du ----
    short8 w2ihhi[2], w2ihlo[2], w2hhhi, w2hhlo;
    {
        int g2 = ty * 32 + 4 * w + du;
        #pragma unroll
        for (int s = 0; s < 2; ++s)
          #pragma unroll
          for (int i = 0; i < 8; ++i) {
              float wv = W_ih2[g2 * 64 + 32*s + 8*lq + i];
              float wh = hi_masked(wv);
              w2ihhi[s][i] = (short)bf_hi_bits(wv);
              w2ihlo[s][i] = (short)bf_hi_bits(wv - wh);
          }
        #pragma unroll
        for (int i = 0; i < 8; ++i) {
            float wv = W_hh2[g2 * 32 + 8*lq + i];
            float wh = hi_masked(wv);
            w2hhhi[i] = (short)bf_hi_bits(wv);
            w2hhlo[i] = (short)bf_hi_bits(wv - wh);
        }
    }
    float bias2[4];
    #pragma unroll
    for (int r = 0; r < 4; ++r)
        bias2[r] = b_ih2[r*32 + 4*w + lq] + b_hh2[r*32 + 4*w + lq];

    // ---- y tile (wave 0): A row 0 = W_out ----
    short8 wouthi = {}, woutlo = {};
    if (w == 0) {
        #pragma unroll
        for (int i = 0; i < 8; ++i) {
            float wv = (lb == 0) ? W_out[8*lq + i] : 0.0f;
            float wh = hi_masked(wv);
            wouthi[i] = (short)bf_hi_bits(wv);
            woutlo[i] = (short)bf_hi_bits(wv - wh);
        }
    }
    const float bout = b_out[0];

    // ---- prologue: stage chunk 0 of x/d (wave1: x, wave2: d) ----
    float4 vx = {0,0,0,0}, vd = {0,0,0,0};
    if (w == 1) vx = *(const float4*)(x_in  + bglob * T + 4*lq);
    if (w == 2) vd = *(const float4*)(dly_in + bglob * T + 4*lq);
    if (w == 1) *(float4*)&XB[0][lq][lb][0] = vx;
    if (w == 2) *(float4*)&DB[0][lq][lb][0] = vd;

    float c1a = 0.f, c1b = 0.f, c2 = 0.f;
    float* op = out + bglob * T;

    const int fro  = lb * 136 + 8 * lq;   // h1 fragment element offset
    const int h2ro = lb * 72  + 8 * lq;   // h2 fragment element offset
    const int u2   = 4 * w + lq;          // L2 ACT unit
    const int u10  = 8 * w + lq;          // L1 ACT unit, tile j=0
    const int u11  = 8 * w + 4 + lq;      //                tile j=1

    BARRIER();

    // step t: L1 computes h1[t] (t<T); L2 computes h2[t-1] (1<=t<=T);
    // wave 0 emits y[t-2] (t>=2). Slot parity: h1[t] -> t&1; h2[tau] -> tau&1.
    #pragma unroll 1
    for (int t = 0; t <= T + 1; ++t) {
        const int pw = t & 1, pr = pw ^ 1;
        const int ts = t & 15, par = (t >> 4) & 1;

        // issue next x/d chunk loads (stay in flight across barriers)
        if (ts == 0 && t + 16 < T) {
            if (w == 1) vx = *(const float4*)(x_in  + bglob * T + (t + 16) + 4*lq);
            if (w == 2) vd = *(const float4*)(dly_in + bglob * T + (t + 16) + 4*lq);
        }

        const us* h1r = &H1[pr][0][0];     // h1[t-1]
        const us* h2r = &H2[pw][0][0];     // h2[t-2]

        short8 hh0 = {}, hh1 = {}, hl0 = {}, hl1 = {}, b0 = {}, b1 = {};
        if (t <= T) {                      // shared by L1 and L2
            hh0 = *(const short8*)(h1r + fro);
            hh1 = *(const short8*)(h1r + fro + 32);
            hl0 = *(const short8*)(h1r + fro + 64);
            hl1 = *(const short8*)(h1r + fro + 96);
        }
        if (t >= 1) {                      // shared by L2 and y
            b0 = *(const short8*)(h2r + h2ro);
            b1 = *(const short8*)(h2r + h2ro + 32);
        }

        // ---------- L2: h2[t-1] = f(h1[t-1], h2[t-2]) ----------
        if (t >= 1 && t <= T) {
            f32x4 qA = {0,0,0,0}, qB = {0,0,0,0};
            qA = MFMA16(w2ihhi[0], hh0, qA);
            qA = MFMA16(w2ihhi[0], hl0, qA);
            qA = MFMA16(w2ihlo[0], hh0, qA);
            qA = MFMA16(w2hhhi,    b0,  qA);
            qA = MFMA16(w2hhlo,    b0,  qA);
            qB = MFMA16(w2ihhi[1], hh1, qB);
            qB = MFMA16(w2ihhi[1], hl1, qB);
            qB = MFMA16(w2ihlo[1], hh1, qB);
            qB = MFMA16(w2hhhi,    b1,  qB);
            float g0 = qA[0] + qB[0] + bias2[0];
            float g1 = qA[1] + qB[1] + bias2[1];
            float g2 = qA[2] + qB[2] + bias2[2];
            float g3 = qA[3] + qB[3] + bias2[3];
            float h2v = lstm_unit(g0, g1, g2, g3, c2);
            split_store(&H2[pr][lb][u2], &H2[pr][lb][32 + u2], h2v);
        }

        // ---------- y[t-2] = W_out . h2[t-2] + b (wave 0) ----------
        if (w == 0 && t >= 2) {
            f32x4 yA = {0,0,0,0}, yB = {0,0,0,0};
            yA = MFMA16(wouthi, b0, yA);
            yA = MFMA16(woutlo, b0, yA);
            yB = MFMA16(wouthi, b1, yB);
            if (lq == 0) op[t - 2] = yA[0] + yB[0] + bout;
        }

        // ---------- L1: h1[t] = f(x[t], d[t], h1[t-1]) ----------
        if (t < T) {
            float xv = XB[par][ts >> 2][lb][ts & 3];
            float dv = DB[par][ts >> 2][lb][ts & 3];
            f32x4 aA0 = {0,0,0,0}, aB0 = {0,0,0,0};
            f32x4 aA1 = {0,0,0,0}, aB1 = {0,0,0,0};
            aA0 = MFMA16(w1hi[0][0], hh0, aA0);
            aA0 = MFMA16(w1hi[0][0], hl0, aA0);
            aA0 = MFMA16(w1lo[0][0], hh0, aA0);
            aB0 = MFMA16(w1hi[0][1], hh1, aB0);
            aB0 = MFMA16(w1hi[0][1], hl1, aB0);
            aB0 = MFMA16(w1lo[0][1], hh1, aB0);
            aA1 = MFMA16(w1hi[1][0], hh0, aA1);
            aA1 = MFMA16(w1hi[1][0], hl0, aA1);
            aA1 = MFMA16(w1lo[1][0], hh0, aA1);
            aB1 = MFMA16(w1hi[1][1], hh1, aB1);
            aB1 = MFMA16(w1hi[1][1], hl1, aB1);
            aB1 = MFMA16(w1lo[1][1], hh1, aB1);

            float gi0 = aA0[0] + aB0[0] + bias1[0][0] + wxx[0][0]*xv + wxd[0][0]*dv;
            float gf0 = aA0[1] + aB0[1] + bias1[0][1] + wxx[0][1]*xv + wxd[0][1]*dv;
            float gg0 = aA0[2] + aB0[2] + bias1[0][2] + wxx[0][2]*xv + wxd[0][2]*dv;
            float go0 = aA0[3] + aB0[3] + bias1[0][3] + wxx[0][3]*xv + wxd[0][3]*dv;
            float h1v0 = lstm_unit(gi0, gf0, gg0, go0, c1a);
            split_store(&H1[pw][lb][u10], &H1[pw][lb][64 + u10], h1v0);

            float gi1 = aA1[0] + aB1[0] + bias1[1][0] + wxx[1][0]*xv + wxd[1][0]*dv;
            float gf1 = aA1[1] + aB1[1] + bias1[1][1] + wxx[1][1]*xv + wxd[1][1]*dv;
            float gg1 = aA1[2] + aB1[2] + bias1[1][2] + wxx[1][2]*xv + wxd[1][2]*dv;
            float go1 = aA1[3] + aB1[3] + bias1[1][3] + wxx[1][3]*xv + wxd[1][3]*dv;
            float h1v1 = lstm_unit(gi1, gf1, gg1, go1, c1b);
            split_store(&H1[pw][lb][u11], &H1[pw][lb][64 + u11], h1v1);
        }

        // publish staged next-chunk x/d right before the chunk-boundary barrier
        if (ts == 15 && t + 1 < T) {
            if (w == 1) *(float4*)&XB[par ^ 1][lq][lb][0] = vx;
            if (w == 2) *(float4*)&DB[par ^ 1][lq][lb][0] = vd;
        }

        BARRIER();
    }
}

extern "C" void kernel_launch(void* const* d_in, const int* in_sizes, int n_in,
                              void* d_out, int out_size, void* d_ws, size_t ws_size,
                              hipStream_t stream) {
    lstm_ar_kernel<<<dim3(64), dim3(512), 0, stream>>>(
        (const float*)d_in[0],  (const float*)d_in[1],
        (const float*)d_in[2],  (const float*)d_in[3],
        (const float*)d_in[4],  (const float*)d_in[5],
        (const float*)d_in[6],  (const float*)d_in[7],
        (const float*)d_in[8],  (const float*)d_in[9],
        (const float*)d_in[10], (const float*)d_in[11],
        (float*)d_out);
}

// Round 3
// 1405.929 us; speedup vs baseline: 1.1204x; 1.1204x over previous
//
#include <hip/hip_runtime.h>

// LSTMAutoRegressive: B=1024, T=1024, H1=64, H2=32, n_in=n_out=1.
// v3: 64 wgs x 512 threads (8 waves). Each wave: 2 L1 tiles + 1 L2 tile
// (MFMA 16x16x32 bf16, swapped operands, gate-permuted A rows, bf16 hi/lo).
// Chain surgery vs v2: all MFMA chains depth<=3; L1 issued before ACT2;
// x/d per-lane register prefetch (no LDS staging); h1 unit-permuted LDS
// layout -> packed b32 h-writes; 4-step unrolled body (static indexing).

using short8 = __attribute__((ext_vector_type(8))) short;   // 8 bf16
using f32x4  = __attribute__((ext_vector_type(4))) float;   // C/D frag
typedef unsigned short us;

#define MFMA16(A,B,C) __builtin_amdgcn_mfma_f32_16x16x32_bf16((A),(B),(C),0,0,0)
// LDS-publish barrier: drain local ops only; globals stay in flight.
#define BARRIER() asm volatile("s_waitcnt lgkmcnt(0)\n\ts_barrier" ::: "memory")

__device__ __forceinline__ us bf_hi_bits(float f){
    union { float f; unsigned u; } v; v.f = f;
    return (us)(v.u >> 16);
}
__device__ __forceinline__ float hi_masked(float f){
    union { float f; unsigned u; } v; v.f = f;
    v.u &= 0xFFFF0000u; return v.f;
}
__device__ __forceinline__ float sigf(float x){
    float e = __expf(-x);
    return __fdividef(1.0f, 1.0f + e);
}
__device__ __forceinline__ float tanhf_fast(float x){
    float e = __expf(-2.0f * x);
    return __fdividef(1.0f - e, 1.0f + e);
}
__device__ __forceinline__ float lstm_unit(float gi, float gf, float gg, float go, float& c){
    float ig = sigf(gi), fg = sigf(gf), gt = tanhf_fast(gg), og = sigf(go);
    c = fg * c + ig * gt;
    return og * tanhf_fast(c);
}
// h1 position permutation: pos p (0..63) -> unit u, so that lane (w,lq)'s two
// units (m=0,1) land at adjacent positions 8w+2lq, 8w+2lq+1.
__device__ __forceinline__ int upos(int p){
    return 8 * (p >> 3) + 4 * (p & 1) + ((p & 7) >> 1);
}

__global__ __launch_bounds__(512, 2)
void lstm_ar_kernel(const float* __restrict__ x_in,
                    const float* __restrict__ dly_in,
                    const float* __restrict__ W_ih1, const float* __restrict__ W_hh1,
                    const float* __restrict__ b_ih1, const float* __restrict__ b_hh1,
                    const float* __restrict__ W_ih2, const float* __restrict__ W_hh2,
                    const float* __restrict__ b_ih2, const float* __restrict__ b_hh2,
                    const float* __restrict__ W_out, const float* __restrict__ b_out,
                    float* __restrict__ out)
{
    // h1 rows: permuted-unit order, [hi 0..63][lo 64..127], stride 136 us.
    // h2 rows: unit order, [hi 0..31][lo 32..63], stride 72 us.
    __shared__ __align__(16) us H1[2][16][136];
    __shared__ __align__(16) us H2[2][16][72];

    const int tid = threadIdx.x;
    const int w   = tid >> 6;          // wave 0..7
    const int l   = tid & 63;
    const int lb  = l & 15;            // A-row / batch column
    const int lq  = l >> 4;            // quarter-wave
    const int T   = 1024;
    const int bglob = blockIdx.x * 16 + lb;

    for (int i = tid; i < 2*16*136; i += 512) ((us*)H1)[i] = 0;
    for (int i = tid; i < 2*16*72;  i += 512) ((us*)H2)[i] = 0;

    const int ty = lb & 3, du = lb >> 2;

    // ---- Layer-1 A-frags (k-order = permuted h1 layout) ----
    short8 w1hi[2][2], w1lo[2][2];
    #pragma unroll
    for (int m = 0; m < 2; ++m)
      #pragma unroll
      for (int s = 0; s < 2; ++s)
        #pragma unroll
        for (int i = 0; i < 8; ++i) {
            int G = ty * 64 + 8 * w + 4 * m + du;
            float wv = W_hh1[G * 64 + upos(32*s + 8*lq + i)];
            float wh = hi_masked(wv);
            w1hi[m][s][i] = (short)bf_hi_bits(wv);
            w1lo[m][s][i] = (short)bf_hi_bits(wv - wh);
        }
    // ACT-1 params: lane unit u(m) = 8w + 4m + lq
    float bias1[2][4], wxx[2][4], wxd[2][4];
    #pragma unroll
    for (int m = 0; m < 2; ++m)
      #pragma unroll
      for (int r = 0; r < 4; ++r) {
          int g = r * 64 + 8 * w + 4 * m + lq;
          bias1[m][r] = b_ih1[g] + b_hh1[g];
          wxx[m][r]   = W_ih1[g*2 + 0];
          wxd[m][r]   = W_ih1[g*2 + 1];
      }

    // ---- Layer-2 A-frags: W_ih2 over permuted h1, W_hh2 over h2 ----
    short8 w2ihhi[2], w2ihlo[2], w2hhhi, w2hhlo;
    {
        int G2 = ty * 32 + 4 * w + du;
        #pragma unroll
        for (int s = 0; s < 2; ++s)
          #pragma unroll
          for (int i = 0; i < 8; ++i) {
              float wv = W_ih2[G2 * 64 + upos(32*s + 8*lq + i)];
              float wh = hi_masked(wv);
              w2ihhi[s][i] = (short)bf_hi_bits(wv);
              w2ihlo[s][i] = (short)bf_hi_bits(wv - wh);
          }
        #pragma unroll
        for (int i = 0; i < 8; ++i) {
            float wv = W_hh2[G2 * 32 + 8*lq + i];
            float wh = hi_masked(wv);
            w2hhhi[i] = (short)bf_hi_bits(wv);
            w2hhlo[i] = (short)bf_hi_bits(wv - wh);
        }
    }
    float bias2[4];
    #pragma unroll
    for (int r = 0; r < 4; ++r)
        bias2[r] = b_ih2[r*32 + 4*w + lq] + b_hh2[r*32 + 4*w + lq];

    // ---- y tile (wave 0): A row 0 = W_out (h2 unit order) ----
    short8 wouthi = {}, woutlo = {};
    if (w == 0) {
        #pragma unroll
        for (int i = 0; i < 8; ++i) {
            float wv = (lb == 0) ? W_out[8*lq + i] : 0.0f;
            float wh = hi_masked(wv);
            wouthi[i] = (short)bf_hi_bits(wv);
            woutlo[i] = (short)bf_hi_bits(wv - wh);
        }
    }
    const float bout = b_out[0];

    const float* xp = x_in   + bglob * T;
    const float* dp = dly_in + bglob * T;
    float*       op = out    + bglob * T;

    float c1a = 0.f, c1b = 0.f, c2 = 0.f;
    const int fro  = lb * 136 + 8 * lq;
    const int h2ro = lb * 72  + 8 * lq;
    const int u2   = 4 * w + lq;
    const int wp   = 8 * w + 2 * lq;    // packed h1 write position (even)

    // x/d register windows: xc = window W (4 steps), xn = W+1 in flight
    float4 xc = *(const float4*)(xp);
    float4 dc = *(const float4*)(dp);
    float4 xn, dn;

    BARRIER();

    // step t: L1 -> h1[t] (t<T); L2 -> h2[t-1] (1<=t<=T); y[t-2] (t>=2).
    #pragma unroll 1
    for (int W = 0; W <= 256; ++W) {
        {   // issue next x/d window (clamped; in flight for 4 steps)
            int Wn = W + 1 < 256 ? W + 1 : 255;
            xn = *(const float4*)(xp + 4 * Wn);
            dn = *(const float4*)(dp + 4 * Wn);
        }
        #pragma unroll
        for (int k = 0; k < 4; ++k) {
            const int t = 4 * W + k;
            if (t <= T + 1) {
                const int pw = t & 1, pr = pw ^ 1;
                const us* h1r = &H1[pr][0][0];   // h1[t-1]
                const us* h2r = &H2[pw][0][0];   // h2[t-2]

                short8 hh0 = *(const short8*)(h1r + fro);
                short8 hh1 = *(const short8*)(h1r + fro + 32);
                short8 hl0 = *(const short8*)(h1r + fro + 64);
                short8 hl1 = *(const short8*)(h1r + fro + 96);
                short8 b0  = *(const short8*)(h2r + h2ro);
                short8 b1  = *(const short8*)(h2r + h2ro + 32);

                const float xv = xc[k], dv = dc[k];
                // xd partials (off-chain, issue early)
                float px0[4], px1[4];
                #pragma unroll
                for (int r = 0; r < 4; ++r) {
                    px0[r] = bias1[0][r] + wxx[0][r]*xv + wxd[0][r]*dv;
                    px1[r] = bias1[1][r] + wxx[1][r]*xv + wxd[1][r]*dv;
                }

                // ---- L1 MFMAs: 4 chains of 3 ----
                f32x4 aA0 = {0,0,0,0}, aB0 = {0,0,0,0};
                f32x4 aA1 = {0,0,0,0}, aB1 = {0,0,0,0};
                aA0 = MFMA16(w1hi[0][0], hh0, aA0);
                aB0 = MFMA16(w1hi[0][1], hh1, aB0);
                aA1 = MFMA16(w1hi[1][0], hh0, aA1);
                aB1 = MFMA16(w1hi[1][1], hh1, aB1);
                aA0 = MFMA16(w1hi[0][0], hl0, aA0);
                aB0 = MFMA16(w1hi[0][1], hl1, aB0);
                aA1 = MFMA16(w1hi[1][0], hl0, aA1);
                aB1 = MFMA16(w1hi[1][1], hl1, aB1);
                aA0 = MFMA16(w1lo[0][0], hh0, aA0);
                aB0 = MFMA16(w1lo[0][1], hh1, aB0);
                aA1 = MFMA16(w1lo[1][0], hh0, aA1);
                aB1 = MFMA16(w1lo[1][1], hh1, aB1);

                // ---- L2 MFMAs: 3 chains of 3 ----
                f32x4 qA = {0,0,0,0}, qB = {0,0,0,0}, qC = {0,0,0,0};
                qA = MFMA16(w2ihhi[0], hh0, qA);
                qB = MFMA16(w2ihhi[1], hh1, qB);
                qC = MFMA16(w2hhhi,    b0,  qC);
                qA = MFMA16(w2ihhi[0], hl0, qA);
                qB = MFMA16(w2ihhi[1], hl1, qB);
                qC = MFMA16(w2hhhi,    b1,  qC);
                qA = MFMA16(w2ihlo[0], hh0, qA);
                qB = MFMA16(w2ihlo[1], hh1, qB);
                qC = MFMA16(w2hhlo,    b0,  qC);

                // ---- y MFMAs (wave 0): 2 chains ----
                f32x4 yA = {0,0,0,0}, yB = {0,0,0,0};
                if (w == 0) {
                    yA = MFMA16(wouthi, b0, yA);
                    yB = MFMA16(wouthi, b1, yB);
                    yA = MFMA16(woutlo, b0, yA);
                }

                // ---- ACT-1 + packed h1 writes (critical cycle closes here) ----
                if (t < T) {
                    float h0 = lstm_unit(aA0[0]+aB0[0]+px0[0], aA0[1]+aB0[1]+px0[1],
                                         aA0[2]+aB0[2]+px0[2], aA0[3]+aB0[3]+px0[3], c1a);
                    float h1 = lstm_unit(aA1[0]+aB1[0]+px1[0], aA1[1]+aB1[1]+px1[1],
                                         aA1[2]+aB1[2]+px1[2], aA1[3]+aB1[3]+px1[3], c1b);
                    unsigned hp0 = __float_as_uint(h0) >> 16;
                    unsigned hp1 = __float_as_uint(h1) >> 16;
                    float hf0 = hi_masked(h0), hf1 = hi_masked(h1);
                    unsigned lp0 = bf_hi_bits(h0 - hf0);
                    unsigned lp1 = bf_hi_bits(h1 - hf1);
                    *(unsigned*)&H1[pw][lb][wp]      = hp0 | (hp1 << 16);
                    *(unsigned*)&H1[pw][lb][64 + wp] = lp0 | (lp1 << 16);
                }

                // ---- ACT-2 + h2 write ----
                if (t >= 1 && t <= T) {
                    float h2v = lstm_unit(qA[0]+qB[0]+qC[0]+bias2[0],
                                          qA[1]+qB[1]+qC[1]+bias2[1],
                                          qA[2]+qB[2]+qC[2]+bias2[2],
                                          qA[3]+qB[3]+qC[3]+bias2[3], c2);
                    unsigned uu = __float_as_uint(h2v);
                    H2[pr][lb][u2] = (us)(uu >> 16);
                    float hf = __uint_as_float(uu & 0xFFFF0000u);
                    H2[pr][lb][32 + u2] = bf_hi_bits(h2v - hf);
                }

                // ---- y store ----
                if (w == 0 && t >= 2 && lq == 0)
                    op[t - 2] = yA[0] + yB[0] + bout;

                BARRIER();
            }
        }
        xc = xn; dc = dn;
    }
}

extern "C" void kernel_launch(void* const* d_in, const int* in_sizes, int n_in,
                              void* d_out, int out_size, void* d_ws, size_t ws_size,
                              hipStream_t stream) {
    lstm_ar_kernel<<<dim3(64), dim3(512), 0, stream>>>(
        (const float*)d_in[0],  (const float*)d_in[1],
        (const float*)d_in[2],  (const float*)d_in[3],
        (const float*)d_in[4],  (const float*)d_in[5],
        (const float*)d_in[6],  (const float*)d_in[7],
        (const float*)d_in[8],  (const float*)d_in[9],
        (const float*)d_in[10], (const float*)d_in[11],
        (float*)d_out);
}

// Round 5
// 791.554 us; speedup vs baseline: 1.9901x; 1.7762x over previous
//
#include <hip/hip_runtime.h>

// LSTMAutoRegressive: B=1024, T=1024, H1=64, H2=32, n_in=n_out=1.
// v5 = v4 with ex2 via __builtin_amdgcn_exp2f (compiler-visible trans op;
// raw asm v_exp_f32 lacked the CDNA trans->VALU wait state -> corruption).
// 64 wgs x 512 threads. ROLE-SPLIT waves: w0-3 = layer-1 only (4 tiles
// each), w4-7 = layer-2 only (2 tiles) + y on w4. exp2-folded activations
// (scales baked into bf16 hi/lo weight split), x/d/bias folded into a 7th
// MFMA k-step (quarter-replicated, A pre-divided by 4). One lgkm-only
// barrier per step. MFMA 16x16x32 bf16, swapped operands, gate-permuted
// A-rows, bf16 hi/lo split for ~fp32 accuracy.

using short8 = __attribute__((ext_vector_type(8))) short;
using f32x4  = __attribute__((ext_vector_type(4))) float;
typedef unsigned short us;
typedef unsigned int   uu;

#define MFMA16(A,B,C) __builtin_amdgcn_mfma_f32_16x16x32_bf16((A),(B),(C),0,0,0)
// LDS-publish barrier: drain local ops only; global loads/stores stay in flight.
#define BARRIER() asm volatile("s_waitcnt lgkmcnt(0)\n\ts_barrier" ::: "memory")

constexpr int   T     = 1024;
constexpr float LOG2E = 1.44269504088896f;

__device__ __forceinline__ us    bhi(float f){ return (us)(__float_as_uint(f) >> 16); }
__device__ __forceinline__ float hmask(float f){ return __uint_as_float(__float_as_uint(f) & 0xFFFF0000u); }
// k-pos -> unit permutations (match the packed h write layouts)
__device__ __forceinline__ int upos1(int p){ return 16*(p>>4) + 4*(p&3) + ((p>>2)&3); }
__device__ __forceinline__ int upos2(int p){ return 8*(p>>3) + 4*(p&1) + ((p&7)>>1); }

__device__ __forceinline__ float rcpf(float x){ return __builtin_amdgcn_rcpf(x); }
#if __has_builtin(__builtin_amdgcn_exp2f)
__device__ __forceinline__ float ex2(float x){ return __builtin_amdgcn_exp2f(x); }
#else
// s_nop inside the asm guarantees the trans->VALU wait state
__device__ __forceinline__ float ex2(float x){
    float r; asm("v_exp_f32 %0, %1\n\ts_nop 0" : "=v"(r) : "v"(x)); return r;
}
#endif

// gates pre-scaled: i,f,o by -log2e ; g by +2log2e. c updated, returns h.
__device__ __forceinline__ float actf(const f32x4 a, float& c){
    float Ei = ex2(a[0]), Ef = ex2(a[1]), Eg = ex2(a[2]), Eo = ex2(a[3]);
    float si = rcpf(1.0f + Ei), sf = rcpf(1.0f + Ef);
    float rg = rcpf(1.0f + Eg), so = rcpf(1.0f + Eo);
    float gt = __builtin_fmaf(-2.0f, rg, 1.0f);         // tanh(g)
    c = sf * c + si * gt;
    float Ec = ex2(c * (2.0f * LOG2E));
    float th = __builtin_fmaf(-2.0f, rcpf(1.0f + Ec), 1.0f);  // tanh(c)
    return so * th;
}

__global__ __launch_bounds__(512)
void lstm_ar_kernel(const float* __restrict__ x_in,
                    const float* __restrict__ dly_in,
                    const float* __restrict__ W_ih1, const float* __restrict__ W_hh1,
                    const float* __restrict__ b_ih1, const float* __restrict__ b_hh1,
                    const float* __restrict__ W_ih2, const float* __restrict__ W_hh2,
                    const float* __restrict__ b_ih2, const float* __restrict__ b_hh2,
                    const float* __restrict__ W_out, const float* __restrict__ b_out,
                    float* __restrict__ out)
{
    // h1 rows: pos-order [hi 0..63 | lo 64..127], stride 136 us (272B).
    // h2 rows: pos-order [hi 0..31 | lo 32..63],  stride 72 us (144B).
    __shared__ __align__(16) us H1[2][16][136];
    __shared__ __align__(16) us H2[2][16][72];

    const int tid = threadIdx.x, w = tid >> 6, l = tid & 63;
    const int lb = l & 15, lq = l >> 4;
    const int bglob = blockIdx.x * 16 + lb;

    for (int i = tid; i < 2*16*136; i += 512) ((us*)H1)[i] = 0;
    for (int i = tid; i < 2*16*72;  i += 512) ((us*)H2)[i] = 0;

    const int ty = lb & 3, du = lb >> 2;
    const float srow = (ty == 2) ? 2.0f * LOG2E : -LOG2E;
    const bool isL1 = (w < 4);
    const int  w2   = w - 4;

    // Shared fragment storage (roles overlay; all indices static after unroll)
    // L1: F[2m+s]=Whi, F[8+2m+s]=Wlo, F[16+m]=xd-frag    (m=0..3, s=0..1)
    // L2: F[2j+s]=ih_hi, F[4+2j+s]=ih_lo, F[8+j]=hh_hi, F[10+j]=hh_lo,
    //     F[12+j]=bias, F[14],F[15]=wout hi/lo           (j=0..1)
    short8 F[20];
    #pragma unroll
    for (int i = 0; i < 20; ++i) F[i] = (short8){0,0,0,0,0,0,0,0};
    float C[4] = {0.f, 0.f, 0.f, 0.f};

    if (isL1) {
        #pragma unroll
        for (int m = 0; m < 4; ++m) {
            const int G = ty * 64 + 16 * w + 4 * m + du;
            #pragma unroll
            for (int s = 0; s < 2; ++s)
                #pragma unroll
                for (int i = 0; i < 8; ++i) {
                    int p = 32*s + 8*lq + i;
                    float v = srow * W_hh1[G * 64 + upos1(p)];
                    float vh = hmask(v);
                    F[2*m+s][i]   = (short)bhi(v);
                    F[8+2*m+s][i] = (short)bhi(v - vh);
                }
            // xd/bias k-step frag, quarter-replicated -> pre-divide by 4
            float q4 = 0.25f * srow;
            float wx = q4 * W_ih1[G*2+0], wd = q4 * W_ih1[G*2+1];
            float bb = q4 * (b_ih1[G] + b_hh1[G]);
            float wxh = hmask(wx), wdh = hmask(wd), bbh = hmask(bb);
            F[16+m] = (short8){ (short)bhi(wx), (short)bhi(wx), (short)bhi(wd),
                                (short)bhi(wd), (short)bhi(bb), (short)bhi(wx - wxh),
                                (short)bhi(wd - wdh), (short)bhi(bb - bbh) };
        }
    } else {
        #pragma unroll
        for (int j = 0; j < 2; ++j) {
            const int G = ty * 32 + 8 * w2 + 4 * j + du;
            #pragma unroll
            for (int s = 0; s < 2; ++s)
                #pragma unroll
                for (int i = 0; i < 8; ++i) {
                    int p = 32*s + 8*lq + i;
                    float v = srow * W_ih2[G * 64 + upos1(p)];
                    float vh = hmask(v);
                    F[2*j+s][i]   = (short)bhi(v);
                    F[4+2*j+s][i] = (short)bhi(v - vh);
                }
            #pragma unroll
            for (int i = 0; i < 8; ++i) {
                int p = 8*lq + i;
                float v = srow * W_hh2[G * 32 + upos2(p)];
                float vh = hmask(v);
                F[8+j][i]  = (short)bhi(v);
                F[10+j][i] = (short)bhi(v - vh);
            }
            float bb = 0.25f * srow * (b_ih2[G] + b_hh2[G]);
            float bbh = hmask(bb);
            F[12+j][0] = (short)bhi(bb);
            F[12+j][1] = (short)bhi(bb - bbh);
        }
        if (w == 4) {   // y tile: A row 0 = W_out over h2 pos-order, unscaled
            #pragma unroll
            for (int i = 0; i < 8; ++i) {
                float v = (lb == 0) ? W_out[upos2(8*lq + i)] : 0.0f;
                float vh = hmask(v);
                F[14][i] = (short)bhi(v);
                F[15][i] = (short)bhi(v - vh);
            }
        }
    }
    const float bout = b_out[0];

    const float* xp = x_in   + bglob * T;
    const float* dp = dly_in + bglob * T;
    float*       op = out    + bglob * T;

    float2 xc = {0,0}, dc = {0,0};
    if (isL1) { xc = *(const float2*)xp; dc = *(const float2*)dp; }

    __syncthreads();

    auto STEP = [&](const int t, const int pw, const int pr,
                    const float xv, const float dv) {
        if (isL1) {
            if (t < T) {
                const us* r = &H1[pr][lb][0];
                short8 hh0 = *(const short8*)(r + 8*lq);
                short8 hh1 = *(const short8*)(r + 32 + 8*lq);
                short8 hl0 = *(const short8*)(r + 64 + 8*lq);
                short8 hl1 = *(const short8*)(r + 96 + 8*lq);
                // xd B-frag: [xhi,xlo,dhi,dlo,1,xhi,dhi,1] (all quarters)
                uu xu = __float_as_uint(xv), duu = __float_as_uint(dv);
                float xlo = xv - __uint_as_float(xu & 0xFFFF0000u);
                float dlo = dv - __uint_as_float(duu & 0xFFFF0000u);
                short8 bx;
                ((uu*)&bx)[0] = (xu >> 16)  | (__float_as_uint(xlo) & 0xFFFF0000u);
                ((uu*)&bx)[1] = (duu >> 16) | (__float_as_uint(dlo) & 0xFFFF0000u);
                ((uu*)&bx)[2] = 0x00003F80u | (xu & 0xFFFF0000u);
                ((uu*)&bx)[3] = (duu >> 16) | 0x3F800000u;

                f32x4 A[4];
                #pragma unroll
                for (int m = 0; m < 4; ++m) A[m] = (f32x4){0,0,0,0};
                #pragma unroll
                for (int m = 0; m < 4; ++m) A[m] = MFMA16(F[2*m],   hh0, A[m]);
                #pragma unroll
                for (int m = 0; m < 4; ++m) A[m] = MFMA16(F[2*m+1], hh1, A[m]);
                #pragma unroll
                for (int m = 0; m < 4; ++m) A[m] = MFMA16(F[2*m],   hl0, A[m]);
                #pragma unroll
                for (int m = 0; m < 4; ++m) A[m] = MFMA16(F[2*m+1], hl1, A[m]);
                #pragma unroll
                for (int m = 0; m < 4; ++m) A[m] = MFMA16(F[8+2*m],   hh0, A[m]);
                #pragma unroll
                for (int m = 0; m < 4; ++m) A[m] = MFMA16(F[8+2*m+1], hh1, A[m]);
                #pragma unroll
                for (int m = 0; m < 4; ++m) A[m] = MFMA16(F[16+m], bx, A[m]);

                float hv[4];
                #pragma unroll
                for (int m = 0; m < 4; ++m) hv[m] = actf(A[m], C[m]);

                uu p0 = (__float_as_uint(hv[0]) >> 16) | (__float_as_uint(hv[1]) & 0xFFFF0000u);
                uu p1 = (__float_as_uint(hv[2]) >> 16) | (__float_as_uint(hv[3]) & 0xFFFF0000u);
                float e0 = hv[0]-hmask(hv[0]), e1 = hv[1]-hmask(hv[1]);
                float e2 = hv[2]-hmask(hv[2]), e3 = hv[3]-hmask(hv[3]);
                uu q0 = (__float_as_uint(e0) >> 16) | (__float_as_uint(e1) & 0xFFFF0000u);
                uu q1 = (__float_as_uint(e2) >> 16) | (__float_as_uint(e3) & 0xFFFF0000u);
                uint2 P = {p0, p1}, Q = {q0, q1};
                *(uint2*)&H1[pw][lb][16*w + 4*lq]      = P;
                *(uint2*)&H1[pw][lb][64 + 16*w + 4*lq] = Q;
            }
        } else {
            if (t >= 2 && w == 4) {     // y[t-2] from h2[t-2] (independent, issue first)
                const us* r2p = &H2[pw][lb][0];
                short8 g0 = *(const short8*)(r2p + 8*lq);
                short8 g1 = *(const short8*)(r2p + 32 + 8*lq);
                f32x4 ya = (f32x4){0,0,0,0};
                ya = MFMA16(F[14], g0, ya);
                ya = MFMA16(F[14], g1, ya);
                ya = MFMA16(F[15], g0, ya);
                if (lq == 0) op[t-2] = ya[0] + bout;
            }
            if (t >= 1 && t <= T) {
                const us* r1 = &H1[pr][lb][0];
                const us* r2 = &H2[pw][lb][0];
                short8 hh0 = *(const short8*)(r1 + 8*lq);
                short8 hh1 = *(const short8*)(r1 + 32 + 8*lq);
                short8 hl0 = *(const short8*)(r1 + 64 + 8*lq);
                short8 hl1 = *(const short8*)(r1 + 96 + 8*lq);
                short8 g0  = *(const short8*)(r2 + 8*lq);
                short8 g1  = *(const short8*)(r2 + 32 + 8*lq);
                const short8 bB = (short8){(short)0x3F80,(short)0x3F80,0,0,0,0,0,0};

                f32x4 Q[2];
                #pragma unroll
                for (int j = 0; j < 2; ++j) Q[j] = (f32x4){0,0,0,0};
                #pragma unroll
                for (int j = 0; j < 2; ++j) Q[j] = MFMA16(F[2*j],   hh0, Q[j]);
                #pragma unroll
                for (int j = 0; j < 2; ++j) Q[j] = MFMA16(F[2*j+1], hh1, Q[j]);
                #pragma unroll
                for (int j = 0; j < 2; ++j) Q[j] = MFMA16(F[2*j],   hl0, Q[j]);
                #pragma unroll
                for (int j = 0; j < 2; ++j) Q[j] = MFMA16(F[2*j+1], hl1, Q[j]);
                #pragma unroll
                for (int j = 0; j < 2; ++j) Q[j] = MFMA16(F[4+2*j],   hh0, Q[j]);
                #pragma unroll
                for (int j = 0; j < 2; ++j) Q[j] = MFMA16(F[4+2*j+1], hh1, Q[j]);
                #pragma unroll
                for (int j = 0; j < 2; ++j) Q[j] = MFMA16(F[8+j],  g0, Q[j]);
                #pragma unroll
                for (int j = 0; j < 2; ++j) Q[j] = MFMA16(F[8+j],  g1, Q[j]);
                #pragma unroll
                for (int j = 0; j < 2; ++j) Q[j] = MFMA16(F[10+j], g0, Q[j]);
                #pragma unroll
                for (int j = 0; j < 2; ++j) Q[j] = MFMA16(F[12+j], bB, Q[j]);

                float h0 = actf(Q[0], C[0]);
                float h1 = actf(Q[1], C[1]);
                uu ph = (__float_as_uint(h0) >> 16) | (__float_as_uint(h1) & 0xFFFF0000u);
                float e0 = h0 - hmask(h0), e1 = h1 - hmask(h1);
                uu pl = (__float_as_uint(e0) >> 16) | (__float_as_uint(e1) & 0xFFFF0000u);
                *(uu*)&H2[pr][lb][8*w2 + 2*lq]      = ph;
                *(uu*)&H2[pr][lb][32 + 8*w2 + 2*lq] = pl;
            }
        }
        BARRIER();
    };

    #pragma unroll 1
    for (int tt = 0; tt <= 512; ++tt) {
        float2 xn = xc, dn = dc;
        if (isL1) {
            const int wn = (tt < 511) ? tt + 1 : 511;
            xn = *(const float2*)(xp + 2*wn);
            dn = *(const float2*)(dp + 2*wn);
        }
        STEP(2*tt,     0, 1, xc.x, dc.x);
        STEP(2*tt + 1, 1, 0, xc.y, dc.y);
        xc = xn; dc = dn;
    }
}

extern "C" void kernel_launch(void* const* d_in, const int* in_sizes, int n_in,
                              void* d_out, int out_size, void* d_ws, size_t ws_size,
                              hipStream_t stream) {
    lstm_ar_kernel<<<dim3(64), dim3(512), 0, stream>>>(
        (const float*)d_in[0],  (const float*)d_in[1],
        (const float*)d_in[2],  (const float*)d_in[3],
        (const float*)d_in[4],  (const float*)d_in[5],
        (const float*)d_in[6],  (const float*)d_in[7],
        (const float*)d_in[8],  (const float*)d_in[9],
        (const float*)d_in[10], (const float*)d_in[11],
        (float*)d_out);
}